// Round 1
// baseline (251.023 us; speedup 1.0000x reference)
//
#include <hip/hip_runtime.h>

// GCN classifier, algebraically folded:
//   out = P (x @ (W1 @ W2)) + (bias[0] * sum(W2) + b2[0])
// where P = D^-1/2 (A + I) D^-1/2.  NUM_CLASSES == 1 makes the whole MLP a
// single 48-vector dot per node, and linearity lets us propagate scalars.

constexpr int kNodes  = 100000;
constexpr int kEdges  = 1600000;
constexpr int kFeat   = 48;
constexpr int kHidden = 256;

// ws layout: [0,256) bytes: w[48] + c (floats, padded)
//            then deg[int N], dinv[float N], y[float N]

__global__ void prep_kernel(const float* __restrict__ W1,
                            const float* __restrict__ bias,
                            const float* __restrict__ W2,
                            const float* __restrict__ b2,
                            float* __restrict__ wc) {
    int t = threadIdx.x;
    if (t < kFeat) {
        float acc = 0.f;
        #pragma unroll 8
        for (int j = 0; j < kHidden; ++j) acc += W1[t * kHidden + j] * W2[j];
        wc[t] = acc;
    } else if (t == kFeat) {
        float s = 0.f;
        for (int j = 0; j < kHidden; ++j) s += W2[j];
        wc[kFeat] = bias[0] * s + b2[0];
    }
}

__global__ void degree_kernel(const int* __restrict__ col, int* __restrict__ deg) {
    int q = blockIdx.x * blockDim.x + threadIdx.x;
    int e = q * 4;
    if (e < kEdges) {
        int4 c = *reinterpret_cast<const int4*>(col + e);
        atomicAdd(&deg[c.x], 1);
        atomicAdd(&deg[c.y], 1);
        atomicAdd(&deg[c.z], 1);
        atomicAdd(&deg[c.w], 1);
    }
}

__global__ void node_kernel(const float* __restrict__ x,
                            const float* __restrict__ wc,
                            const int* __restrict__ deg,
                            float* __restrict__ dinv,
                            float* __restrict__ y,
                            float* __restrict__ out) {
    __shared__ float sw[kFeat];
    __shared__ float sc;
    if (threadIdx.x < kFeat) sw[threadIdx.x] = wc[threadIdx.x];
    if (threadIdx.x == kFeat) sc = wc[kFeat];
    __syncthreads();

    int i = blockIdx.x * blockDim.x + threadIdx.x;
    if (i < kNodes) {
        const float4* xp = reinterpret_cast<const float4*>(x + (size_t)i * kFeat);
        float acc = 0.f;
        #pragma unroll
        for (int k = 0; k < kFeat / 4; ++k) {
            float4 v = xp[k];
            acc += v.x * sw[4 * k + 0] + v.y * sw[4 * k + 1]
                 + v.z * sw[4 * k + 2] + v.w * sw[4 * k + 3];
        }
        // self-loop makes deg >= 1; reference's max(deg,1) is a no-op
        float d  = (float)(deg[i] + 1);
        float di = rsqrtf(d);
        dinv[i] = di;
        y[i]    = acc;
        out[i]  = di * di * acc + sc;   // self-loop contribution + constant
    }
}

__global__ void scatter_kernel(const int* __restrict__ row,
                               const int* __restrict__ col,
                               const float* __restrict__ dinv,
                               const float* __restrict__ y,
                               float* __restrict__ out) {
    int q = blockIdx.x * blockDim.x + threadIdx.x;
    int e = q * 4;
    if (e < kEdges) {
        int4 r = *reinterpret_cast<const int4*>(row + e);
        int4 c = *reinterpret_cast<const int4*>(col + e);
        atomicAdd(&out[c.x], dinv[r.x] * dinv[c.x] * y[r.x]);
        atomicAdd(&out[c.y], dinv[r.y] * dinv[c.y] * y[r.y]);
        atomicAdd(&out[c.z], dinv[r.z] * dinv[c.z] * y[r.z]);
        atomicAdd(&out[c.w], dinv[r.w] * dinv[c.w] * y[r.w]);
    }
}

extern "C" void kernel_launch(void* const* d_in, const int* in_sizes, int n_in,
                              void* d_out, int out_size, void* d_ws, size_t ws_size,
                              hipStream_t stream) {
    const float* x    = (const float*)d_in[0];
    const int*   ei   = (const int*)d_in[1];   // [2, E]: rows then cols
    const float* W1   = (const float*)d_in[2];
    const float* bias = (const float*)d_in[3];
    const float* W2   = (const float*)d_in[4];
    const float* b2   = (const float*)d_in[5];
    float*       out  = (float*)d_out;

    const int* row = ei;
    const int* col = ei + kEdges;

    float* wc   = (float*)d_ws;
    char*  p    = (char*)d_ws + 256;
    int*   deg  = (int*)p;
    float* dinv = (float*)(p + (size_t)kNodes * 4);
    float* y    = (float*)(p + 2 * (size_t)kNodes * 4);

    hipMemsetAsync(deg, 0, (size_t)kNodes * sizeof(int), stream);

    prep_kernel<<<1, 64, 0, stream>>>(W1, bias, W2, b2, wc);

    int edgeQuads  = kEdges / 4;
    int edgeBlocks = (edgeQuads + 255) / 256;
    degree_kernel<<<edgeBlocks, 256, 0, stream>>>(col, deg);

    int nodeBlocks = (kNodes + 255) / 256;
    node_kernel<<<nodeBlocks, 256, 0, stream>>>(x, wc, deg, dinv, y, out);

    scatter_kernel<<<edgeBlocks, 256, 0, stream>>>(row, col, dinv, y, out);
}

// Round 2
// 132.406 us; speedup vs baseline: 1.8959x; 1.8959x over previous
//
#include <hip/hip_runtime.h>

// GCN classifier, algebraically folded:
//   out = P (x @ (W1 @ W2)) + (bias[0] * sum(W2) + b2[0]),  P = D^-1/2 (A+I) D^-1/2
// NUM_CLASSES==1 collapses the MLP to one 48-vector dot per node; linearity lets
// us propagate scalars. Edge aggregation is done WITHOUT global atomics:
// edges are bucketed by destination (512 ids/bucket -> LDS-sized), then degree
// and weighted-sum are bucket-local LDS atomics. (R1's global-atomic scatter
// cost 32B of HBM write traffic per atomic: 92us for 1.6M edges.)

constexpr int kNodes  = 100000;
constexpr int kEdges  = 1600000;
constexpr int kFeat   = 48;
constexpr int kHidden = 256;

constexpr int kBShift = 9;                               // 512 node ids / bucket
constexpr int kBSize  = 1 << kBShift;
constexpr int kNB     = (kNodes + kBSize - 1) / kBSize;  // 196 buckets
constexpr int kCap    = 10240;   // slots/bucket; mean load 8163, sigma~90
constexpr int kEPB    = 4096;    // edges per bucketing block (16/thread)

__global__ void prep_kernel(const float* __restrict__ W1,
                            const float* __restrict__ bias,
                            const float* __restrict__ W2,
                            const float* __restrict__ b2,
                            float* __restrict__ wc) {
    int t = threadIdx.x;
    if (t < kFeat) {
        float acc = 0.f;
        #pragma unroll 8
        for (int j = 0; j < kHidden; ++j) acc += W1[t * kHidden + j] * W2[j];
        wc[t] = acc;
    } else if (t == kFeat) {
        float s = 0.f;
        for (int j = 0; j < kHidden; ++j) s += W2[j];
        wc[kFeat] = bias[0] * s + b2[0];
    }
}

// Scatter edges into per-destination-bucket regions. Packed entry:
// (localcol << 17) | row   (row < 2^17, localcol < 2^9).
__global__ __launch_bounds__(256) void bucket_kernel(const int* __restrict__ row,
                                                     const int* __restrict__ col,
                                                     int* __restrict__ cursor,
                                                     int* __restrict__ bpacked) {
    __shared__ int hist[kNB];
    for (int t = threadIdx.x; t < kNB; t += 256) hist[t] = 0;
    __syncthreads();

    int base = blockIdx.x * kEPB;
    int cols[16];
    #pragma unroll
    for (int k = 0; k < 16; ++k) {
        int e = base + k * 256 + threadIdx.x;
        cols[k] = (e < kEdges) ? col[e] : -1;
        if (cols[k] >= 0) atomicAdd(&hist[cols[k] >> kBShift], 1);
    }
    __syncthreads();
    // one global atomic per (block,bucket): reserve a contiguous run
    for (int t = threadIdx.x; t < kNB; t += 256) {
        int c = hist[t];
        hist[t] = c ? atomicAdd(&cursor[t], c) : 0;  // hist becomes local cursor
    }
    __syncthreads();
    #pragma unroll
    for (int k = 0; k < 16; ++k) {
        int e = base + k * 256 + threadIdx.x;
        if (e < kEdges) {
            int c = cols[k];
            int b = c >> kBShift;
            int slot = atomicAdd(&hist[b], 1);
            if (slot < kCap) {
                int r = row[e];
                bpacked[b * kCap + slot] = ((c & (kBSize - 1)) << 17) | r;
            }
        }
    }
}

__global__ __launch_bounds__(1024) void degree_kernel(const int* __restrict__ cursor,
                                                      const int* __restrict__ bpacked,
                                                      int* __restrict__ deg) {
    __shared__ int sdeg[kBSize];
    int b = blockIdx.x;
    if (threadIdx.x < kBSize) sdeg[threadIdx.x] = 0;
    __syncthreads();
    int n = min(cursor[b], kCap);
    int base = b * kCap;
    for (int i = threadIdx.x; i < n; i += 1024)
        atomicAdd(&sdeg[bpacked[base + i] >> 17], 1);
    __syncthreads();
    int node = b * kBSize + threadIdx.x;
    if (threadIdx.x < kBSize && node < kNodes) deg[node] = sdeg[threadIdx.x];
}

// Per node: y = dot(x_i, w); dinv = rsqrt(deg+1); dy = dinv*y;
// out init = self-loop term + constant.
__global__ __launch_bounds__(256) void node_kernel(const float* __restrict__ x,
                                                   const float* __restrict__ wc,
                                                   const int* __restrict__ deg,
                                                   float* __restrict__ dinv,
                                                   float* __restrict__ dy,
                                                   float* __restrict__ out) {
    __shared__ float sw[kFeat];
    __shared__ float sc;
    if (threadIdx.x < kFeat) sw[threadIdx.x] = wc[threadIdx.x];
    if (threadIdx.x == kFeat) sc = wc[kFeat];
    __syncthreads();

    int i = blockIdx.x * blockDim.x + threadIdx.x;
    if (i < kNodes) {
        const float4* xp = reinterpret_cast<const float4*>(x + (size_t)i * kFeat);
        float acc = 0.f;
        #pragma unroll
        for (int k = 0; k < kFeat / 4; ++k) {
            float4 v = xp[k];
            acc += v.x * sw[4 * k + 0] + v.y * sw[4 * k + 1]
                 + v.z * sw[4 * k + 2] + v.w * sw[4 * k + 3];
        }
        float d  = (float)(deg[i] + 1);    // +1 self-loop; deg>=1 so max(d,1) no-op
        float di = rsqrtf(d);
        dinv[i] = di;
        dy[i]   = di * acc;
        out[i]  = di * di * acc + sc;      // self-loop contribution + constant
    }
}

__global__ __launch_bounds__(1024) void agg_kernel(const int* __restrict__ cursor,
                                                   const int* __restrict__ bpacked,
                                                   const float* __restrict__ dy,
                                                   const float* __restrict__ dinv,
                                                   float* __restrict__ out) {
    __shared__ float ssum[kBSize];
    int b = blockIdx.x;
    if (threadIdx.x < kBSize) ssum[threadIdx.x] = 0.f;
    __syncthreads();
    int n = min(cursor[b], kCap);
    int base = b * kCap;
    for (int i = threadIdx.x; i < n; i += 1024) {
        int p = bpacked[base + i];
        float v = dy[p & 0x1FFFF];         // L2-resident gather (400 KB table)
        atomicAdd(&ssum[p >> 17], v);      // ds_add_f32, bucket-local
    }
    __syncthreads();
    int node = b * kBSize + threadIdx.x;
    if (threadIdx.x < kBSize && node < kNodes)
        out[node] += dinv[node] * ssum[threadIdx.x];
}

extern "C" void kernel_launch(void* const* d_in, const int* in_sizes, int n_in,
                              void* d_out, int out_size, void* d_ws, size_t ws_size,
                              hipStream_t stream) {
    const float* x    = (const float*)d_in[0];
    const int*   ei   = (const int*)d_in[1];   // [2, E]: rows then cols
    const float* W1   = (const float*)d_in[2];
    const float* bias = (const float*)d_in[3];
    const float* W2   = (const float*)d_in[4];
    const float* b2   = (const float*)d_in[5];
    float*       out  = (float*)d_out;

    const int* row = ei;
    const int* col = ei + kEdges;

    // ws layout
    char*  p       = (char*)d_ws;
    float* wc      = (float*)p;                 p += 256;
    int*   cursor  = (int*)p;                   p += 1024;           // kNB ints, padded
    int*   deg     = (int*)p;                   p += (size_t)kNodes * 4;
    float* dinv    = (float*)p;                 p += (size_t)kNodes * 4;
    float* dy      = (float*)p;                 p += (size_t)kNodes * 4;
    int*   bpacked = (int*)p;                   // kNB * kCap ints (~8 MB)

    hipMemsetAsync(cursor, 0, kNB * sizeof(int), stream);

    prep_kernel<<<1, 64, 0, stream>>>(W1, bias, W2, b2, wc);

    int bucketBlocks = (kEdges + kEPB - 1) / kEPB;   // 391
    bucket_kernel<<<bucketBlocks, 256, 0, stream>>>(row, col, cursor, bpacked);

    degree_kernel<<<kNB, 1024, 0, stream>>>(cursor, bpacked, deg);

    int nodeBlocks = (kNodes + 255) / 256;
    node_kernel<<<nodeBlocks, 256, 0, stream>>>(x, wc, deg, dinv, dy, out);

    agg_kernel<<<kNB, 1024, 0, stream>>>(cursor, bpacked, dy, dinv, out);
}

// Round 3
// 115.781 us; speedup vs baseline: 2.1681x; 1.1436x over previous
//
#include <hip/hip_runtime.h>

// GCN classifier, algebraically folded:
//   out = P (x @ (W1 @ W2)) + (bias[0]*sum(W2) + b2[0]),  P = D^-1/2 (A+I) D^-1/2
// NUM_CLASSES==1 collapses the MLP to one 48-vector dot per node (z = x.w);
// linearity lets us propagate scalars. Edge aggregation uses destination
// bucketing (512 ids/bucket) so degree & weighted-sum are LDS atomics, not
// global atomics (R1: 3.2M global atomics cost ~180us).
// R3: 4 dispatches: prep(+cursor clear) -> fat(bucket edges + z) ->
//     degfin(degree+dinv+dy, deg never leaves LDS) -> agg(sum + final combine).

constexpr int kNodes  = 100000;
constexpr int kEdges  = 1600000;
constexpr int kFeat   = 48;
constexpr int kHidden = 256;

constexpr int kBShift = 9;                               // 512 node ids / bucket
constexpr int kBSize  = 1 << kBShift;
constexpr int kNB     = (kNodes + kBSize - 1) / kBSize;  // 196 buckets
constexpr int kCap    = 10240;   // slots/bucket; mean 8163, sigma~90 -> 23 sd
constexpr int kEPB    = 8192;    // edges per bucketing block (32/thread)
constexpr int kQuads  = kEdges / 4;                      // 400000 (exact)
constexpr int kBBlk   = (kEdges + kEPB - 1) / kEPB;      // 196 bucket blocks
constexpr int kZBlk   = (kNodes + 255) / 256;            // 391 z blocks

// prep: w[t] = sum_j W1[t][j]*W2[j]; c = bias[0]*sum(W2)+b2[0]; clear cursor.
__global__ __launch_bounds__(256) void prep_kernel(const float* __restrict__ W1,
                                                   const float* __restrict__ bias,
                                                   const float* __restrict__ W2,
                                                   const float* __restrict__ b2,
                                                   float* __restrict__ wc,
                                                   int* __restrict__ cursor) {
    __shared__ float w1t[kHidden * kFeat];   // transposed: [j][t], 49 KB
    __shared__ float sw2[kHidden];
    __shared__ float red[256];
    int tid = threadIdx.x;
    for (int g = tid; g < kFeat * kHidden; g += 256) {
        int r = g >> 8, j = g & 255;         // coalesced read, 2-way-bank LDS write
        w1t[j * kFeat + r] = W1[g];
    }
    float v = W2[tid];
    sw2[tid] = v;
    red[tid] = v;
    if (tid < kNB) cursor[tid] = 0;
    __syncthreads();
    // block reduce sum(W2)
    for (int s = 128; s > 0; s >>= 1) {
        if (tid < s) red[tid] += red[tid + s];
        __syncthreads();
    }
    if (tid < kFeat) {
        float acc = 0.f;
        #pragma unroll 8
        for (int j = 0; j < kHidden; ++j) acc += w1t[j * kFeat + tid] * sw2[j];
        wc[tid] = acc;
    }
    if (tid == 0) wc[kFeat] = bias[0] * red[0] + b2[0];
}

// Fat kernel: blocks [0,kBBlk) bucket edges; blocks [kBBlk, kBBlk+kZBlk) compute z.
// Packed entry: (localcol << 17) | row  (row < 2^17, localcol < 2^9).
__global__ __launch_bounds__(256) void fat_kernel(const int* __restrict__ row,
                                                  const int* __restrict__ col,
                                                  const float* __restrict__ x,
                                                  const float* __restrict__ wc,
                                                  int* __restrict__ cursor,
                                                  int* __restrict__ bpacked,
                                                  float* __restrict__ z) {
    if (blockIdx.x < kBBlk) {
        __shared__ int hist[kNB];
        int tid = threadIdx.x;
        for (int t = tid; t < kNB; t += 256) hist[t] = 0;
        __syncthreads();

        int qbase = blockIdx.x * (kEPB / 4);
        const int4* colq = reinterpret_cast<const int4*>(col);
        const int4* rowq = reinterpret_cast<const int4*>(row);
        int4 c4[8];
        #pragma unroll
        for (int k = 0; k < 8; ++k) {
            int q = qbase + k * 256 + tid;
            if (q < kQuads) {
                int4 c = colq[q];
                c4[k] = c;
                atomicAdd(&hist[c.x >> kBShift], 1);
                atomicAdd(&hist[c.y >> kBShift], 1);
                atomicAdd(&hist[c.z >> kBShift], 1);
                atomicAdd(&hist[c.w >> kBShift], 1);
            } else {
                c4[k] = make_int4(-1, -1, -1, -1);
            }
        }
        __syncthreads();
        // one global atomic per (block,bucket): reserve a contiguous run
        for (int t = tid; t < kNB; t += 256) {
            int c = hist[t];
            hist[t] = c ? atomicAdd(&cursor[t], c) : 0;  // hist -> local cursor
        }
        __syncthreads();
        #pragma unroll
        for (int k = 0; k < 8; ++k) {
            int q = qbase + k * 256 + tid;
            if (q < kQuads) {
                int4 r = rowq[q];
                int cs[4] = {c4[k].x, c4[k].y, c4[k].z, c4[k].w};
                int rs[4] = {r.x, r.y, r.z, r.w};
                #pragma unroll
                for (int u = 0; u < 4; ++u) {
                    int c = cs[u], b = c >> kBShift;
                    int slot = atomicAdd(&hist[b], 1);
                    if (slot < kCap)
                        bpacked[b * kCap + slot] = ((c & (kBSize - 1)) << 17) | rs[u];
                }
            }
        }
    } else {
        // z = x . w
        __shared__ float sw[kFeat];
        if (threadIdx.x < kFeat) sw[threadIdx.x] = wc[threadIdx.x];
        __syncthreads();
        int i = (blockIdx.x - kBBlk) * 256 + threadIdx.x;
        if (i < kNodes) {
            const float4* xp = reinterpret_cast<const float4*>(x + (size_t)i * kFeat);
            float acc = 0.f;
            #pragma unroll
            for (int k = 0; k < kFeat / 4; ++k) {
                float4 v = xp[k];
                acc += v.x * sw[4 * k + 0] + v.y * sw[4 * k + 1]
                     + v.z * sw[4 * k + 2] + v.w * sw[4 * k + 3];
            }
            z[i] = acc;
        }
    }
}

// Degree from bucket entries (LDS only) + per-node finalize: dinv, dy = dinv*z.
__global__ __launch_bounds__(1024) void degfin_kernel(const int* __restrict__ cursor,
                                                      const int* __restrict__ bpacked,
                                                      const float* __restrict__ z,
                                                      float* __restrict__ dinv,
                                                      float* __restrict__ dy) {
    __shared__ int sdeg[kBSize];
    int b = blockIdx.x, tid = threadIdx.x;
    if (tid < kBSize) sdeg[tid] = 0;
    __syncthreads();
    int n = min(cursor[b], kCap);
    int base = b * kCap;
    const int4* bq = reinterpret_cast<const int4*>(bpacked + base);
    int nq = n >> 2;
    for (int i = tid; i < nq; i += 1024) {
        int4 p = bq[i];
        atomicAdd(&sdeg[p.x >> 17], 1);
        atomicAdd(&sdeg[p.y >> 17], 1);
        atomicAdd(&sdeg[p.z >> 17], 1);
        atomicAdd(&sdeg[p.w >> 17], 1);
    }
    if (tid < (n & 3)) atomicAdd(&sdeg[bpacked[base + (n & ~3) + tid] >> 17], 1);
    __syncthreads();
    int node = b * kBSize + tid;
    if (tid < kBSize && node < kNodes) {
        float d  = (float)(sdeg[tid] + 1);   // +1 self-loop; max(d,1) is a no-op
        float di = rsqrtf(d);
        dinv[node] = di;
        dy[node]   = di * z[node];
    }
}

// Aggregate dy over in-edges (LDS atomics) + final combine:
// out = dinv*(ssum + dy) + c    (dinv*dy == dinv^2*z == self-loop term)
__global__ __launch_bounds__(1024) void agg_kernel(const int* __restrict__ cursor,
                                                   const int* __restrict__ bpacked,
                                                   const float* __restrict__ dy,
                                                   const float* __restrict__ dinv,
                                                   const float* __restrict__ wc,
                                                   float* __restrict__ out) {
    __shared__ float ssum[kBSize];
    int b = blockIdx.x, tid = threadIdx.x;
    if (tid < kBSize) ssum[tid] = 0.f;
    __syncthreads();
    int n = min(cursor[b], kCap);
    int base = b * kCap;
    const int4* bq = reinterpret_cast<const int4*>(bpacked + base);
    int nq = n >> 2;
    for (int i = tid; i < nq; i += 1024) {
        int4 p = bq[i];
        atomicAdd(&ssum[p.x >> 17], dy[p.x & 0x1FFFF]);  // L2-resident gathers
        atomicAdd(&ssum[p.y >> 17], dy[p.y & 0x1FFFF]);
        atomicAdd(&ssum[p.z >> 17], dy[p.z & 0x1FFFF]);
        atomicAdd(&ssum[p.w >> 17], dy[p.w & 0x1FFFF]);
    }
    if (tid < (n & 3)) {
        int p = bpacked[base + (n & ~3) + tid];
        atomicAdd(&ssum[p >> 17], dy[p & 0x1FFFF]);
    }
    __syncthreads();
    int node = b * kBSize + tid;
    if (tid < kBSize && node < kNodes)
        out[node] = dinv[node] * (ssum[tid] + dy[node]) + wc[kFeat];
}

extern "C" void kernel_launch(void* const* d_in, const int* in_sizes, int n_in,
                              void* d_out, int out_size, void* d_ws, size_t ws_size,
                              hipStream_t stream) {
    const float* x    = (const float*)d_in[0];
    const int*   ei   = (const int*)d_in[1];   // [2, E]: rows then cols
    const float* W1   = (const float*)d_in[2];
    const float* bias = (const float*)d_in[3];
    const float* W2   = (const float*)d_in[4];
    const float* b2   = (const float*)d_in[5];
    float*       out  = (float*)d_out;

    const int* row = ei;
    const int* col = ei + kEdges;

    // ws layout
    char*  p       = (char*)d_ws;
    float* wc      = (float*)p;                 p += 256;
    int*   cursor  = (int*)p;                   p += 1024;           // kNB ints
    float* z       = (float*)p;                 p += (size_t)kNodes * 4;
    float* dinv    = (float*)p;                 p += (size_t)kNodes * 4;
    float* dy      = (float*)p;                 p += (size_t)kNodes * 4;
    int*   bpacked = (int*)p;                   // kNB * kCap ints (~8 MB)

    prep_kernel<<<1, 256, 0, stream>>>(W1, bias, W2, b2, wc, cursor);
    fat_kernel<<<kBBlk + kZBlk, 256, 0, stream>>>(row, col, x, wc, cursor, bpacked, z);
    degfin_kernel<<<kNB, 1024, 0, stream>>>(cursor, bpacked, z, dinv, dy);
    agg_kernel<<<kNB, 1024, 0, stream>>>(cursor, bpacked, dy, dinv, wc, out);
}